// Round 1
// baseline (18109.464 us; speedup 1.0000x reference)
//
#include <hip/hip_runtime.h>
#include <math.h>

#define NLAYER 6
#define DMODEL 1024
#define NHEAD  16
#define DFFN   4096
#define VOCAB  32000
#define NBATCH 4
#define SEQLEN 512
#define HDIM   64
#define MROWS  (NBATCH*SEQLEN)
#define NEGBIG -1000000000.0f

__device__ __forceinline__ float waveSum(float v) {
#pragma unroll
  for (int off = 32; off > 0; off >>= 1) v += __shfl_xor(v, off);
  return v;
}
__device__ __forceinline__ float waveMax(float v) {
#pragma unroll
  for (int off = 32; off > 0; off >>= 1) v = fmaxf(v, __shfl_xor(v, off));
  return v;
}

// ---- embedding gather: out[r,:] = emb[tok[r],:] ----
__global__ __launch_bounds__(256) void embed_kernel(
    const int* __restrict__ tok, const float* __restrict__ emb,
    float* __restrict__ out)
{
  const long r = blockIdx.x;
  const int t = tok[r];
  const float4* s = (const float4*)(emb + (long)t * DMODEL);
  float4* d = (float4*)(out + r * DMODEL);
  d[threadIdx.x] = s[threadIdx.x];
}

// ---- rope tables: cos/sin[s][i], i<32 ----
__global__ __launch_bounds__(256) void rope_tab_kernel(
    float* __restrict__ cosT, float* __restrict__ sinT)
{
  const int idx = blockIdx.x * 256 + threadIdx.x;   // < SEQLEN*32
  const int s = idx >> 5, i = idx & 31;
  const float e = (float)(2 * i) / 64.0f;
  const float inv = 1.0f / powf(10000.0f, e);
  const float ang = (float)s * inv;
  cosT[idx] = cosf(ang);
  sinT[idx] = sinf(ang);
}

// ---- rope apply in place; X layout (B,S,H,HDIM) ----
__global__ __launch_bounds__(256) void rope_kernel(
    float* __restrict__ X, const float* __restrict__ cosT,
    const float* __restrict__ sinT)
{
  const long idx = (long)blockIdx.x * 256 + threadIdx.x; // (bs,h,i)
  const int i = (int)(idx & 31);
  const long rest = idx >> 5;
  const int h = (int)(rest & 15);
  const long bs = rest >> 4;
  const int s = (int)(bs & (SEQLEN - 1));
  float2* p = (float2*)(X + (bs * NHEAD + h) * HDIM + 2 * i);
  const float2 v = *p;
  const float c = cosT[s * 32 + i], sn = sinT[s * 32 + i];
  float2 o;
  o.x = v.x * c - v.y * sn;
  o.y = v.x * sn + v.y * c;
  *p = o;
}

// ---- generic fp32 GEMM: C = A @ W (+bias)(+relu). 128x64 tile, BK=16.
// Batched via blockIdx.z: A += z*aBatch; W,C += (z>>4)*wBatchB + (z&15)*wBatchH
__global__ __launch_bounds__(256) void gemm_kernel(
    const float* __restrict__ A, const float* __restrict__ W,
    const float* __restrict__ bias, float* __restrict__ C,
    int K, long lda, long ldw, long ldc,
    long aBatch, long wBatchB, long wBatchH, int relu)
{
  __shared__ float As[16][128];   // k-major
  __shared__ float Ws[16][64];    // k-major
  const int tid = threadIdx.x;
  const int z = blockIdx.z;
  const long zb = z >> 4, zh = z & 15;
  const float* Ap = A + (long)z * aBatch;
  const long whOff = zb * wBatchB + zh * wBatchH;
  const float* Wp = W + whOff;
  float* Cp = C + whOff;
  const int row0 = blockIdx.x * 128;
  const int col0 = blockIdx.y * 64;
  const int rm = tid >> 4;        // 0..15 -> rows rm*8..+7
  const int rn = tid & 15;        // cols rn*4..+3
  const int ar = tid >> 1;        // A stage: row 0..127
  const int ac = (tid & 1) * 8;   // A stage: k-offset 0 or 8
  const int wr = tid >> 4;        // W stage: k-row 0..15
  const int wc = (tid & 15) * 4;  // W stage: col
  const float* Aip = Ap + (long)(row0 + ar) * lda + ac;
  const float* Wip = Wp + (long)wr * ldw + col0 + wc;

  float acc[8][4];
#pragma unroll
  for (int i = 0; i < 8; ++i)
#pragma unroll
    for (int j = 0; j < 4; ++j) acc[i][j] = 0.0f;

  for (int k0 = 0; k0 < K; k0 += 16) {
    const float4 a0 = *(const float4*)(Aip + k0);
    const float4 a1 = *(const float4*)(Aip + k0 + 4);
    const float4 wv = *(const float4*)(Wip + (long)k0 * ldw);
    __syncthreads();
    As[ac + 0][ar] = a0.x; As[ac + 1][ar] = a0.y;
    As[ac + 2][ar] = a0.z; As[ac + 3][ar] = a0.w;
    As[ac + 4][ar] = a1.x; As[ac + 5][ar] = a1.y;
    As[ac + 6][ar] = a1.z; As[ac + 7][ar] = a1.w;
    *(float4*)&Ws[wr][wc] = wv;
    __syncthreads();
#pragma unroll
    for (int kk = 0; kk < 16; ++kk) {
      const float4 b  = *(const float4*)&Ws[kk][rn * 4];
      const float4 x0 = *(const float4*)&As[kk][rm * 8];
      const float4 x1 = *(const float4*)&As[kk][rm * 8 + 4];
      const float av[8] = {x0.x, x0.y, x0.z, x0.w, x1.x, x1.y, x1.z, x1.w};
      const float bv[4] = {b.x, b.y, b.z, b.w};
#pragma unroll
      for (int i = 0; i < 8; ++i)
#pragma unroll
        for (int j = 0; j < 4; ++j)
          acc[i][j] = fmaf(av[i], bv[j], acc[i][j]);
    }
  }
  float4 bb = make_float4(0.f, 0.f, 0.f, 0.f);
  if (bias) bb = *(const float4*)(bias + col0 + rn * 4);
#pragma unroll
  for (int i = 0; i < 8; ++i) {
    float4 o;
    o.x = acc[i][0] + bb.x;
    o.y = acc[i][1] + bb.y;
    o.z = acc[i][2] + bb.z;
    o.w = acc[i][3] + bb.w;
    if (relu) {
      o.x = fmaxf(o.x, 0.f); o.y = fmaxf(o.y, 0.f);
      o.z = fmaxf(o.z, 0.f); o.w = fmaxf(o.w, 0.f);
    }
    *(float4*)(Cp + (long)(row0 + rm * 8 + i) * ldc + col0 + rn * 4) = o;
  }
}

// ---- QK^T scores with scale + mask. grid (S/64, S/64, B*H) ----
__global__ __launch_bounds__(256) void scores_kernel(
    const float* __restrict__ Q, const float* __restrict__ Km,
    float* __restrict__ Sc, const int* __restrict__ tok, int causal)
{
  __shared__ float Qs[64][64];   // [d][q]
  __shared__ float Ks[64][64];   // [d][k]
  const int tid = threadIdx.x;
  const int z = blockIdx.z;
  const int b = z >> 4, h = z & 15;
  const int q0 = blockIdx.x * 64, k0 = blockIdx.y * 64;
  const int r = tid & 63;
  const int cg = (tid >> 6) * 16;
  const float* qp = Q + ((long)(b * SEQLEN + q0 + r)) * DMODEL + h * HDIM + cg;
  const float* kp = Km + ((long)(b * SEQLEN + k0 + r)) * DMODEL + h * HDIM + cg;
#pragma unroll
  for (int j = 0; j < 16; j += 4) {
    const float4 qa = *(const float4*)(qp + j);
    const float4 ka = *(const float4*)(kp + j);
    Qs[cg + j + 0][r] = qa.x; Qs[cg + j + 1][r] = qa.y;
    Qs[cg + j + 2][r] = qa.z; Qs[cg + j + 3][r] = qa.w;
    Ks[cg + j + 0][r] = ka.x; Ks[cg + j + 1][r] = ka.y;
    Ks[cg + j + 2][r] = ka.z; Ks[cg + j + 3][r] = ka.w;
  }
  __syncthreads();
  const int rm = tid >> 4, rn = tid & 15;
  float acc[4][4];
#pragma unroll
  for (int i = 0; i < 4; ++i)
#pragma unroll
    for (int j = 0; j < 4; ++j) acc[i][j] = 0.0f;
#pragma unroll 16
  for (int kk = 0; kk < 64; ++kk) {
    const float4 a  = *(const float4*)&Qs[kk][rm * 4];
    const float4 b4 = *(const float4*)&Ks[kk][rn * 4];
    const float av[4] = {a.x, a.y, a.z, a.w};
    const float bv[4] = {b4.x, b4.y, b4.z, b4.w};
#pragma unroll
    for (int i = 0; i < 4; ++i)
#pragma unroll
      for (int j = 0; j < 4; ++j)
        acc[i][j] = fmaf(av[i], bv[j], acc[i][j]);
  }
  const int4 tv = *(const int4*)(tok + b * SEQLEN + k0 + rn * 4);
  const int ta[4] = {tv.x, tv.y, tv.z, tv.w};
#pragma unroll
  for (int i = 0; i < 4; ++i) {
    const int qrow = q0 + rm * 4 + i;
    float vals[4];
#pragma unroll
    for (int j = 0; j < 4; ++j) {
      const int kcol = k0 + rn * 4 + j;
      const bool ok = (ta[j] != 0) && (!causal || kcol <= qrow);
      vals[j] = ok ? acc[i][j] * 0.125f : NEGBIG;
    }
    float4 o; o.x = vals[0]; o.y = vals[1]; o.z = vals[2]; o.w = vals[3];
    *(float4*)(Sc + ((long)z * SEQLEN + qrow) * SEQLEN + k0 + rn * 4) = o;
  }
}

// ---- softmax over rows of length 512, one wave per row ----
__global__ __launch_bounds__(256) void softmax512_kernel(float* __restrict__ Sc)
{
  const int wv = threadIdx.x >> 6, ln = threadIdx.x & 63;
  float* p = Sc + ((long)blockIdx.x * 4 + wv) * SEQLEN + ln * 8;
  float4 a = *(float4*)p;
  float4 b = *(float4*)(p + 4);
  float m = fmaxf(fmaxf(fmaxf(a.x, a.y), fmaxf(a.z, a.w)),
                  fmaxf(fmaxf(b.x, b.y), fmaxf(b.z, b.w)));
  m = waveMax(m);
  const float e0 = expf(a.x - m), e1 = expf(a.y - m), e2 = expf(a.z - m), e3 = expf(a.w - m);
  const float e4 = expf(b.x - m), e5 = expf(b.y - m), e6 = expf(b.z - m), e7 = expf(b.w - m);
  float s = ((e0 + e1) + (e2 + e3)) + ((e4 + e5) + (e6 + e7));
  s = waveSum(s);
  const float inv = 1.0f / s;
  a.x = e0 * inv; a.y = e1 * inv; a.z = e2 * inv; a.w = e3 * inv;
  b.x = e4 * inv; b.y = e5 * inv; b.z = e6 * inv; b.w = e7 * inv;
  *(float4*)p = a;
  *(float4*)(p + 4) = b;
}

// ---- out = LayerNorm(X + R) * g + be ; one block per row of 1024 ----
__global__ __launch_bounds__(256) void ln_kernel(
    const float* __restrict__ X, const float* __restrict__ R,
    const float* __restrict__ g, const float* __restrict__ be,
    float* __restrict__ Out)
{
  __shared__ float red[8];
  const int tid = threadIdx.x;
  const long row = blockIdx.x;
  const float4 xv = *(const float4*)(X + row * DMODEL + tid * 4);
  const float4 rv = *(const float4*)(R + row * DMODEL + tid * 4);
  const float v0 = xv.x + rv.x, v1 = xv.y + rv.y, v2 = xv.z + rv.z, v3 = xv.w + rv.w;
  float s = waveSum((v0 + v1) + (v2 + v3));
  const int wv = tid >> 6, ln = tid & 63;
  if (ln == 0) red[wv] = s;
  __syncthreads();
  const float mu = (red[0] + red[1] + red[2] + red[3]) * (1.0f / DMODEL);
  const float d0 = v0 - mu, d1 = v1 - mu, d2 = v2 - mu, d3 = v3 - mu;
  float sq = waveSum(d0 * d0 + d1 * d1 + d2 * d2 + d3 * d3);
  if (ln == 0) red[4 + wv] = sq;
  __syncthreads();
  const float var = (red[4] + red[5] + red[6] + red[7]) * (1.0f / DMODEL);
  const float rstd = 1.0f / sqrtf(var + 1e-5f);
  const float4 gv = *(const float4*)(g + tid * 4);
  const float4 bv = *(const float4*)(be + tid * 4);
  float4 o;
  o.x = d0 * rstd * gv.x + bv.x;
  o.y = d1 * rstd * gv.y + bv.y;
  o.z = d2 * rstd * gv.z + bv.z;
  o.w = d3 * rstd * gv.w + bv.w;
  *(float4*)(Out + row * DMODEL + tid * 4) = o;
}

// ---- final softmax over V=32000, in place, one block per row ----
__global__ __launch_bounds__(256) void softmax_vocab_kernel(float* __restrict__ P)
{
  __shared__ float red[8];
  const int tid = threadIdx.x;
  float4* p = (float4*)(P + (long)blockIdx.x * VOCAB);
  float m = -3.4e38f;
  for (int i = tid; i < VOCAB / 4; i += 256) {
    const float4 v = p[i];
    m = fmaxf(m, fmaxf(fmaxf(v.x, v.y), fmaxf(v.z, v.w)));
  }
  m = waveMax(m);
  const int wv = tid >> 6, ln = tid & 63;
  if (ln == 0) red[wv] = m;
  __syncthreads();
  m = fmaxf(fmaxf(red[0], red[1]), fmaxf(red[2], red[3]));
  float s = 0.f;
  for (int i = tid; i < VOCAB / 4; i += 256) {
    const float4 v = p[i];
    s += expf(v.x - m) + expf(v.y - m) + expf(v.z - m) + expf(v.w - m);
  }
  s = waveSum(s);
  if (ln == 0) red[4 + wv] = s;
  __syncthreads();
  const float inv = 1.0f / (red[4] + red[5] + red[6] + red[7]);
  for (int i = tid; i < VOCAB / 4; i += 256) {
    float4 v = p[i];
    v.x = expf(v.x - m) * inv;
    v.y = expf(v.y - m) * inv;
    v.z = expf(v.z - m) * inv;
    v.w = expf(v.w - m) * inv;
    p[i] = v;
  }
}

extern "C" void kernel_launch(void* const* d_in, const int* in_sizes, int n_in,
                              void* d_out, int out_size, void* d_ws, size_t ws_size,
                              hipStream_t stream)
{
  (void)in_sizes; (void)n_in; (void)out_size; (void)ws_size;
  const int* src = (const int*)d_in[0];
  const int* tgt = (const int*)d_in[1];
  const float* enc_emb = (const float*)d_in[2];
  const float* dec_emb = (const float*)d_in[3];
  const float* eWq = (const float*)d_in[4];
  const float* eWk = (const float*)d_in[5];
  const float* eWv = (const float*)d_in[6];
  const float* eWo = (const float*)d_in[7];
  const float* eBq = (const float*)d_in[8];
  const float* eBk = (const float*)d_in[9];
  const float* eBv = (const float*)d_in[10];
  const float* eBo = (const float*)d_in[11];
  const float* eL1g = (const float*)d_in[12];
  const float* eL1b = (const float*)d_in[13];
  const float* eL2g = (const float*)d_in[14];
  const float* eL2b = (const float*)d_in[15];
  const float* eF1  = (const float*)d_in[16];
  const float* eF1b = (const float*)d_in[17];
  const float* eF2  = (const float*)d_in[18];
  const float* eF2b = (const float*)d_in[19];
  const float* dsWq = (const float*)d_in[20];
  const float* dsWk = (const float*)d_in[21];
  const float* dsWv = (const float*)d_in[22];
  const float* dsWo = (const float*)d_in[23];
  const float* dcWq = (const float*)d_in[24];
  const float* dcWk = (const float*)d_in[25];
  const float* dcWv = (const float*)d_in[26];
  const float* dcWo = (const float*)d_in[27];
  const float* dsBq = (const float*)d_in[28];
  const float* dsBk = (const float*)d_in[29];
  const float* dsBv = (const float*)d_in[30];
  const float* dsBo = (const float*)d_in[31];
  const float* dcBq = (const float*)d_in[32];
  const float* dcBk = (const float*)d_in[33];
  const float* dcBv = (const float*)d_in[34];
  const float* dcBo = (const float*)d_in[35];
  const float* dL1g = (const float*)d_in[36];
  const float* dL2g = (const float*)d_in[37];
  const float* dL3g = (const float*)d_in[38];
  const float* dL1b = (const float*)d_in[39];
  const float* dL2b = (const float*)d_in[40];
  const float* dL3b = (const float*)d_in[41];
  const float* dF1  = (const float*)d_in[42];
  const float* dF1b = (const float*)d_in[43];
  const float* dF2  = (const float*)d_in[44];
  const float* dF2b = (const float*)d_in[45];
  const float* fW   = (const float*)d_in[46];
  const float* fb   = (const float*)d_in[47];

  // workspace layout (floats). Total ~126 MB.
  float* wp = (float*)d_ws;
  float* cosT = wp; wp += SEQLEN * 32;
  float* sinT = wp; wp += SEQLEN * 32;
  float* xb = wp;   wp += (long)MROWS * DMODEL;   // encoder stream / memory
  float* yb = wp;   wp += (long)MROWS * DMODEL;   // decoder stream
  float* qb = wp;   wp += (long)MROWS * DMODEL;
  float* kb = wp;   wp += (long)MROWS * DMODEL;
  float* vb = wp;   wp += (long)MROWS * DMODEL;
  float* ab = wp;   wp += (long)MROWS * DMODEL;   // attention concat out
  float* pb = wp;   wp += (long)MROWS * DMODEL;   // branch output (a or f)
  float* big = wp;  // scores (B*H*S*S = 16.8M floats) and ffn (8.4M) share
  float* scores = big;
  float* ffn = big;

  rope_tab_kernel<<<(SEQLEN * 32) / 256, 256, 0, stream>>>(cosT, sinT);

  auto gemmL = [&](const float* A, const float* W, const float* bias, float* Cc,
                   int M, int N, int K, int relu) {
    gemm_kernel<<<dim3(M / 128, N / 64, 1), 256, 0, stream>>>(
        A, W, bias, Cc, K, K, N, N, 0, 0, 0, relu);
  };
  auto attention = [&](const float* qin, const float* kvin,
                       const float* Wq, const float* Bq,
                       const float* Wk, const float* Bk,
                       const float* Wv, const float* Bv,
                       const float* Wo, const float* Bo,
                       const int* tok, int causal) {
    gemmL(qin,  Wq, Bq, qb, MROWS, DMODEL, DMODEL, 0);
    gemmL(kvin, Wk, Bk, kb, MROWS, DMODEL, DMODEL, 0);
    gemmL(kvin, Wv, Bv, vb, MROWS, DMODEL, DMODEL, 0);
    rope_kernel<<<(MROWS * NHEAD * 32) / 256, 256, 0, stream>>>(qb, cosT, sinT);
    rope_kernel<<<(MROWS * NHEAD * 32) / 256, 256, 0, stream>>>(kb, cosT, sinT);
    scores_kernel<<<dim3(SEQLEN / 64, SEQLEN / 64, NBATCH * NHEAD), 256, 0, stream>>>(
        qb, kb, scores, tok, causal);
    softmax512_kernel<<<(NBATCH * NHEAD * SEQLEN) / 4, 256, 0, stream>>>(scores);
    // PV: per (b,h): probs(512x512) @ V(512x64) -> ab[b, q, h*64+d]
    gemm_kernel<<<dim3(SEQLEN / 128, 1, NBATCH * NHEAD), 256, 0, stream>>>(
        scores, vb, (const float*)nullptr, ab, SEQLEN,
        SEQLEN, DMODEL, DMODEL,
        (long)SEQLEN * SEQLEN, (long)SEQLEN * DMODEL, (long)HDIM, 0);
    gemmL(ab, Wo, Bo, pb, MROWS, DMODEL, DMODEL, 0);
  };

  const long DD = (long)DMODEL * DMODEL;
  const long DF = (long)DMODEL * DFFN;

  // -------- encoder --------
  embed_kernel<<<MROWS, 256, 0, stream>>>(src, enc_emb, xb);
  for (int l = 0; l < NLAYER; ++l) {
    attention(xb, xb, eWq + l * DD, eBq + l * DMODEL, eWk + l * DD, eBk + l * DMODEL,
              eWv + l * DD, eBv + l * DMODEL, eWo + l * DD, eBo + l * DMODEL, src, 0);
    ln_kernel<<<MROWS, 256, 0, stream>>>(xb, pb, eL1g + l * DMODEL, eL1b + l * DMODEL, xb);
    gemmL(xb,  eF1 + l * DF, eF1b + l * DFFN,   ffn, MROWS, DFFN,   DMODEL, 1);
    gemmL(ffn, eF2 + l * DF, eF2b + l * DMODEL, pb,  MROWS, DMODEL, DFFN,   0);
    ln_kernel<<<MROWS, 256, 0, stream>>>(xb, pb, eL2g + l * DMODEL, eL2b + l * DMODEL, xb);
  }
  // -------- decoder --------
  embed_kernel<<<MROWS, 256, 0, stream>>>(tgt, dec_emb, yb);
  for (int l = 0; l < NLAYER; ++l) {
    attention(yb, yb, dsWq + l * DD, dsBq + l * DMODEL, dsWk + l * DD, dsBk + l * DMODEL,
              dsWv + l * DD, dsBv + l * DMODEL, dsWo + l * DD, dsBo + l * DMODEL, tgt, 1);
    ln_kernel<<<MROWS, 256, 0, stream>>>(yb, pb, dL1g + l * DMODEL, dL1b + l * DMODEL, yb);
    attention(yb, xb, dcWq + l * DD, dcBq + l * DMODEL, dcWk + l * DD, dcBk + l * DMODEL,
              dcWv + l * DD, dcBv + l * DMODEL, dcWo + l * DD, dcBo + l * DMODEL, src, 0);
    ln_kernel<<<MROWS, 256, 0, stream>>>(yb, pb, dL2g + l * DMODEL, dL2b + l * DMODEL, yb);
    gemmL(yb,  dF1 + l * DF, dF1b + l * DFFN,   ffn, MROWS, DFFN,   DMODEL, 1);
    gemmL(ffn, dF2 + l * DF, dF2b + l * DMODEL, pb,  MROWS, DMODEL, DFFN,   0);
    ln_kernel<<<MROWS, 256, 0, stream>>>(yb, pb, dL3g + l * DMODEL, dL3b + l * DMODEL, yb);
  }
  // -------- final projection + softmax (in place in d_out) --------
  float* outp = (float*)d_out;
  gemmL(yb, fW, fb, outp, MROWS, VOCAB, DMODEL, 0);
  softmax_vocab_kernel<<<MROWS, 256, 0, stream>>>(outp);
}

// Round 2
// 8016.152 us; speedup vs baseline: 2.2591x; 2.2591x over previous
//
#include <hip/hip_runtime.h>
#include <math.h>

#define NLAYER 6
#define DMODEL 1024
#define NHEAD  16
#define DFFN   4096
#define VOCAB  32000
#define NBATCH 4
#define SEQLEN 512
#define HDIM   64
#define MROWS  (NBATCH*SEQLEN)
#define NEGBIG -1000000000.0f

typedef __attribute__((ext_vector_type(8))) short bf16x8;
typedef __attribute__((ext_vector_type(4))) float f32x4;

__device__ __forceinline__ float waveSum(float v) {
#pragma unroll
  for (int off = 32; off > 0; off >>= 1) v += __shfl_xor(v, off);
  return v;
}
__device__ __forceinline__ float waveMax(float v) {
#pragma unroll
  for (int off = 32; off > 0; off >>= 1) v = fmaxf(v, __shfl_xor(v, off));
  return v;
}

__device__ __forceinline__ unsigned short f2bf(float x) {
  unsigned u = __float_as_uint(x);
  u += 0x7FFFu + ((u >> 16) & 1u);   // RNE
  return (unsigned short)(u >> 16);
}
__device__ __forceinline__ float bf2f(unsigned short h) {
  return __uint_as_float((unsigned)h << 16);
}

__device__ __forceinline__ void load_lds16(const unsigned short* g, unsigned short* l) {
  __builtin_amdgcn_global_load_lds(
      (const __attribute__((address_space(1))) unsigned int*)g,
      (__attribute__((address_space(3))) unsigned int*)l, 16, 0, 0);
}

// ---- embedding gather ----
__global__ __launch_bounds__(256) void embed_kernel(
    const int* __restrict__ tok, const float* __restrict__ emb,
    float* __restrict__ out)
{
  const long r = blockIdx.x;
  const int t = tok[r];
  const float4* s = (const float4*)(emb + (long)t * DMODEL);
  float4* d = (float4*)(out + r * DMODEL);
  d[threadIdx.x] = s[threadIdx.x];
}

// ---- rope tables ----
__global__ __launch_bounds__(256) void rope_tab_kernel(
    float* __restrict__ cosT, float* __restrict__ sinT)
{
  const int idx = blockIdx.x * 256 + threadIdx.x;   // < SEQLEN*32
  const int s = idx >> 5, i = idx & 31;
  const float e = (float)(2 * i) / 64.0f;
  const float inv = 1.0f / powf(10000.0f, e);
  const float ang = (float)s * inv;
  cosT[idx] = cosf(ang);
  sinT[idx] = sinf(ang);
}

// ---- rope apply in place; X row stride ld, layout (.., h, 64) ----
__global__ __launch_bounds__(256) void rope_kernel(
    float* __restrict__ X, long ld, const float* __restrict__ cosT,
    const float* __restrict__ sinT)
{
  const long idx = (long)blockIdx.x * 256 + threadIdx.x; // (bs,h,i)
  const int i = (int)(idx & 31);
  const long rest = idx >> 5;
  const int h = (int)(rest & 15);
  const long bs = rest >> 4;
  const int s = (int)(bs & (SEQLEN - 1));
  float2* p = (float2*)(X + bs * ld + h * HDIM + 2 * i);
  const float2 v = *p;
  const float c = cosT[s * 32 + i], sn = sinT[s * 32 + i];
  float2 o;
  o.x = v.x * c - v.y * sn;
  o.y = v.x * sn + v.y * c;
  *p = o;
}

// ---- weight convert: W[K][ldN] fp32 -> Wt_hi/lo[(obase+n)][K] bf16 split ----
__global__ __launch_bounds__(256) void wconv_kernel(
    const float* __restrict__ W, unsigned short* __restrict__ Whi,
    unsigned short* __restrict__ Wlo, int K, int ldN, int nbase, int obase)
{
  __shared__ float tile[32][72];
  const int t = threadIdx.x;
  const int k0 = blockIdx.x * 32, n0 = blockIdx.y * 64;
  const int lk = t >> 3, lj = (t & 7) * 8;
  const float* wp = W + (long)(k0 + lk) * ldN + nbase + n0 + lj;
  const float4 a = *(const float4*)wp;
  const float4 b = *(const float4*)(wp + 4);
  tile[lk][lj + 0] = a.x; tile[lk][lj + 1] = a.y;
  tile[lk][lj + 2] = a.z; tile[lk][lj + 3] = a.w;
  tile[lk][lj + 4] = b.x; tile[lk][lj + 5] = b.y;
  tile[lk][lj + 6] = b.z; tile[lk][lj + 7] = b.w;
  __syncthreads();
  const int wn = t >> 2, wk = (t & 3) * 8;
  unsigned int ph[4], pl[4];
#pragma unroll
  for (int i = 0; i < 4; ++i) {
    const float x0 = tile[wk + 2 * i][wn], x1 = tile[wk + 2 * i + 1][wn];
    const unsigned short h0 = f2bf(x0), h1 = f2bf(x1);
    const unsigned short l0 = f2bf(x0 - bf2f(h0)), l1 = f2bf(x1 - bf2f(h1));
    ph[i] = (unsigned)h0 | ((unsigned)h1 << 16);
    pl[i] = (unsigned)l0 | ((unsigned)l1 << 16);
  }
  const long off = (long)(obase + n0 + wn) * K + k0 + wk;
  *(uint4*)(Whi + off) = make_uint4(ph[0], ph[1], ph[2], ph[3]);
  *(uint4*)(Wlo + off) = make_uint4(pl[0], pl[1], pl[2], pl[3]);
}

// ---- concat three 1024-bias into fused 3072 ----
__global__ __launch_bounds__(256) void bias3_kernel(
    const float* __restrict__ b0, const float* __restrict__ b1,
    const float* __restrict__ b2, float* __restrict__ dst)
{
  const int i = blockIdx.x * 256 + threadIdx.x;  // < 3072
  dst[i] = (i < 1024) ? b0[i] : ((i < 2048) ? b1[i - 1024] : b2[i - 2048]);
}

// ---- bf16x3 split GEMM: C = A(fp32) @ W(split bf16 hi/lo, [n][k]) + bias ----
// tile BM x 128, BK=32, 4 waves (2x2), mfma 16x16x32_bf16, 3 mfma/product
template<int BM>
__global__ __launch_bounds__(256) void gemm_bf16_kernel(
    const float* __restrict__ A, const unsigned short* __restrict__ Wh,
    const unsigned short* __restrict__ Wl, const float* __restrict__ bias,
    float* __restrict__ C, int K, long ldc, int relu)
{
  constexpr int WM = BM / 2;
  constexpr int MREP = WM / 16;
  constexpr int F = BM / 8;       // fp32 elems staged per thread for A
  constexpr int TPR = 32 / F;     // threads per A row
  __shared__ __align__(16) unsigned short Ah[BM][40];
  __shared__ __align__(16) unsigned short Al[BM][40];
  __shared__ __align__(16) unsigned short Bh[128][32];
  __shared__ __align__(16) unsigned short Bl[128][32];
  const int tid = threadIdx.x;
  const int wid = tid >> 6, lane = tid & 63;
  const int wr = wid >> 1, wc = wid & 1;
  const int row0 = blockIdx.x * BM, col0 = blockIdx.y * 128;
  const int arow = tid / TPR, akoff = (tid % TPR) * F;
  const float* aptr = A + (long)(row0 + arow) * K + akoff;
  const long bRow = col0 + wid * 32 + (lane >> 2);
  const unsigned short* bhp = Wh + bRow * (long)K + (lane & 3) * 8;
  const unsigned short* blp = Wl + bRow * (long)K + (lane & 3) * 8;
  unsigned short* ldsBh0 = &Bh[wid * 32][0];
  unsigned short* ldsBh1 = &Bh[wid * 32 + 16][0];
  unsigned short* ldsBl0 = &Bl[wid * 32][0];
  unsigned short* ldsBl1 = &Bl[wid * 32 + 16][0];

  f32x4 acc[MREP][4];
#pragma unroll
  for (int i = 0; i < MREP; ++i)
#pragma unroll
    for (int j = 0; j < 4; ++j) acc[i][j] = {0.f, 0.f, 0.f, 0.f};

  const int fr = lane & 15, kg = lane >> 4;

  for (int k0 = 0; k0 < K; k0 += 32) {
    float4 av[F / 4];
#pragma unroll
    for (int i = 0; i < F / 4; ++i)
      av[i] = *(const float4*)(aptr + k0 + i * 4);
    __syncthreads();
    // stage A (convert + split)
    float xs[F];
#pragma unroll
    for (int i = 0; i < F / 4; ++i) {
      xs[4 * i + 0] = av[i].x; xs[4 * i + 1] = av[i].y;
      xs[4 * i + 2] = av[i].z; xs[4 * i + 3] = av[i].w;
    }
#pragma unroll
    for (int g = 0; g < F; g += 8) {
      unsigned int ph[4], pl[4];
#pragma unroll
      for (int i = 0; i < 4; ++i) {
        const float x0 = xs[g + 2 * i], x1 = xs[g + 2 * i + 1];
        const unsigned short h0 = f2bf(x0), h1 = f2bf(x1);
        const unsigned short l0 = f2bf(x0 - bf2f(h0)), l1 = f2bf(x1 - bf2f(h1));
        ph[i] = (unsigned)h0 | ((unsigned)h1 << 16);
        pl[i] = (unsigned)l0 | ((unsigned)l1 << 16);
      }
      *(uint4*)&Ah[arow][akoff + g] = make_uint4(ph[0], ph[1], ph[2], ph[3]);
      *(uint4*)&Al[arow][akoff + g] = make_uint4(pl[0], pl[1], pl[2], pl[3]);
    }
    // stage B (async global->LDS, 16B/lane, linear dest)
    load_lds16(bhp + k0, ldsBh0);
    load_lds16(bhp + k0 + 16 * (long)K, ldsBh1);
    load_lds16(blp + k0, ldsBl0);
    load_lds16(blp + k0 + 16 * (long)K, ldsBl1);
    __syncthreads();
    // fragments
    bf16x8 ah[MREP], alo[MREP], bh[4], bl[4];
#pragma unroll
    for (int m = 0; m < MREP; ++m) {
      ah[m]  = *(const bf16x8*)&Ah[wr * WM + m * 16 + fr][kg * 8];
      alo[m] = *(const bf16x8*)&Al[wr * WM + m * 16 + fr][kg * 8];
    }
#pragma unroll
    for (int n = 0; n < 4; ++n) {
      bh[n] = *(const bf16x8*)&Bh[wc * 64 + n * 16 + fr][kg * 8];
      bl[n] = *(const bf16x8*)&Bl[wc * 64 + n * 16 + fr][kg * 8];
    }
#pragma unroll
    for (int m = 0; m < MREP; ++m)
#pragma unroll
      for (int n = 0; n < 4; ++n) {
        acc[m][n] = __builtin_amdgcn_mfma_f32_16x16x32_bf16(ah[m],  bh[n], acc[m][n], 0, 0, 0);
        acc[m][n] = __builtin_amdgcn_mfma_f32_16x16x32_bf16(ah[m],  bl[n], acc[m][n], 0, 0, 0);
        acc[m][n] = __builtin_amdgcn_mfma_f32_16x16x32_bf16(alo[m], bh[n], acc[m][n], 0, 0, 0);
      }
  }
  // epilogue: C/D layout col=lane&15, row=(lane>>4)*4+r
  const int rgrp = lane >> 4;
  const int ccolBase = col0 + wc * 64 + fr;
  const int crowBase = row0 + wr * WM + rgrp * 4;
#pragma unroll
  for (int n = 0; n < 4; ++n) {
    const int ccol = ccolBase + n * 16;
    const float bv = bias ? bias[ccol] : 0.0f;
#pragma unroll
    for (int m = 0; m < MREP; ++m)
#pragma unroll
      for (int r = 0; r < 4; ++r) {
        float v = acc[m][n][r] + bv;
        if (relu) v = fmaxf(v, 0.0f);
        C[(long)(crowBase + m * 16 + r) * ldc + ccol] = v;
      }
  }
}

// ---- QK^T scores with scale + mask. grid (S/64, S/64, B*H) ----
__global__ __launch_bounds__(256) void scores_kernel(
    const float* __restrict__ Q, const float* __restrict__ Km,
    long ldq, long ldk,
    float* __restrict__ Sc, const int* __restrict__ tok, int causal)
{
  __shared__ float Qs[64][64];   // [d][q]
  __shared__ float Ks[64][64];   // [d][k]
  const int tid = threadIdx.x;
  const int z = blockIdx.z;
  const int b = z >> 4, h = z & 15;
  const int q0 = blockIdx.x * 64, k0 = blockIdx.y * 64;
  const int r = tid & 63;
  const int cg = (tid >> 6) * 16;
  const float* qp = Q + (long)(b * SEQLEN + q0 + r) * ldq + h * HDIM + cg;
  const float* kp = Km + (long)(b * SEQLEN + k0 + r) * ldk + h * HDIM + cg;
#pragma unroll
  for (int j = 0; j < 16; j += 4) {
    const float4 qa = *(const float4*)(qp + j);
    const float4 ka = *(const float4*)(kp + j);
    Qs[cg + j + 0][r] = qa.x; Qs[cg + j + 1][r] = qa.y;
    Qs[cg + j + 2][r] = qa.z; Qs[cg + j + 3][r] = qa.w;
    Ks[cg + j + 0][r] = ka.x; Ks[cg + j + 1][r] = ka.y;
    Ks[cg + j + 2][r] = ka.z; Ks[cg + j + 3][r] = ka.w;
  }
  __syncthreads();
  const int rm = tid >> 4, rn = tid & 15;
  float acc[4][4];
#pragma unroll
  for (int i = 0; i < 4; ++i)
#pragma unroll
    for (int j = 0; j < 4; ++j) acc[i][j] = 0.0f;
#pragma unroll 16
  for (int kk = 0; kk < 64; ++kk) {
    const float4 a  = *(const float4*)&Qs[kk][rm * 4];
    const float4 b4 = *(const float4*)&Ks[kk][rn * 4];
    const float av[4] = {a.x, a.y, a.z, a.w};
    const float bv[4] = {b4.x, b4.y, b4.z, b4.w};
#pragma unroll
    for (int i = 0; i < 4; ++i)
#pragma unroll
      for (int j = 0; j < 4; ++j)
        acc[i][j] = fmaf(av[i], bv[j], acc[i][j]);
  }
  const int4 tv = *(const int4*)(tok + b * SEQLEN + k0 + rn * 4);
  const int ta[4] = {tv.x, tv.y, tv.z, tv.w};
#pragma unroll
  for (int i = 0; i < 4; ++i) {
    const int qrow = q0 + rm * 4 + i;
    float vals[4];
#pragma unroll
    for (int j = 0; j < 4; ++j) {
      const int kcol = k0 + rn * 4 + j;
      const bool ok = (ta[j] != 0) && (!causal || kcol <= qrow);
      vals[j] = ok ? acc[i][j] * 0.125f : NEGBIG;
    }
    float4 o; o.x = vals[0]; o.y = vals[1]; o.z = vals[2]; o.w = vals[3];
    *(float4*)(Sc + ((long)z * SEQLEN + qrow) * SEQLEN + k0 + rn * 4) = o;
  }
}

// ---- softmax over rows of length 512, one wave per row ----
__global__ __launch_bounds__(256) void softmax512_kernel(float* __restrict__ Sc)
{
  const int wv = threadIdx.x >> 6, ln = threadIdx.x & 63;
  float* p = Sc + ((long)blockIdx.x * 4 + wv) * SEQLEN + ln * 8;
  float4 a = *(float4*)p;
  float4 b = *(float4*)(p + 4);
  float m = fmaxf(fmaxf(fmaxf(a.x, a.y), fmaxf(a.z, a.w)),
                  fmaxf(fmaxf(b.x, b.y), fmaxf(b.z, b.w)));
  m = waveMax(m);
  const float e0 = expf(a.x - m), e1 = expf(a.y - m), e2 = expf(a.z - m), e3 = expf(a.w - m);
  const float e4 = expf(b.x - m), e5 = expf(b.y - m), e6 = expf(b.z - m), e7 = expf(b.w - m);
  float s = ((e0 + e1) + (e2 + e3)) + ((e4 + e5) + (e6 + e7));
  s = waveSum(s);
  const float inv = 1.0f / s;
  a.x = e0 * inv; a.y = e1 * inv; a.z = e2 * inv; a.w = e3 * inv;
  b.x = e4 * inv; b.y = e5 * inv; b.z = e6 * inv; b.w = e7 * inv;
  *(float4*)p = a;
  *(float4*)(p + 4) = b;
}

// ---- PV: per (b,h) probs(512x512) @ V(512x64) -> O[b, q, h*64+d], fp32 ----
__global__ __launch_bounds__(256) void pv_kernel(
    const float* __restrict__ S, const float* __restrict__ V,
    float* __restrict__ O)
{
  __shared__ float As[16][128];
  __shared__ float Ws[16][64];
  const int tid = threadIdx.x;
  const int z = blockIdx.z;
  const int b = z >> 4, h = z & 15;
  const float* Ap = S + (long)z * SEQLEN * SEQLEN;
  const float* Wp = V + (long)b * SEQLEN * 3072 + h * HDIM;
  float* Cp = O + (long)b * SEQLEN * DMODEL + h * HDIM;
  const int row0 = blockIdx.x * 128;
  const int rm = tid >> 4, rn = tid & 15;
  const int ar = tid >> 1, ac = (tid & 1) * 8;
  const int wr = tid >> 4, wc = (tid & 15) * 4;
  const float* Aip = Ap + (long)(row0 + ar) * SEQLEN + ac;
  const float* Wip = Wp + (long)wr * 3072 + wc;

  float acc[8][4];
#pragma unroll
  for (int i = 0; i < 8; ++i)
#pragma unroll
    for (int j = 0; j < 4; ++j) acc[i][j] = 0.0f;

  for (int k0 = 0; k0 < SEQLEN; k0 += 16) {
    const float4 a0 = *(const float4*)(Aip + k0);
    const float4 a1 = *(const float4*)(Aip + k0 + 4);
    const float4 wv = *(const float4*)(Wip + (long)k0 * 3072);
    __syncthreads();
    As[ac + 0][ar] = a0.x; As[ac + 1][ar] = a0.y;
    As[ac + 2][ar] = a0.z; As[ac + 3][ar] = a0.w;
    As[ac + 4][ar] = a1.x; As[ac + 5][ar] = a1.y;
    As[ac + 6][ar] = a1.z; As[ac + 7][ar] = a1.w;
    *(float4*)&Ws[wr][wc] = wv;
    __syncthreads();
#pragma unroll
    for (int kk = 0; kk < 16; ++kk) {
      const float4 b4 = *(const float4*)&Ws[kk][rn * 4];
      const float4 x0 = *(const float4*)&As[kk][rm * 8];
      const float4 x1 = *(const float4*)&As[kk][rm * 8 + 4];
      const float av[8] = {x0.x, x0.y, x0.z, x0.w, x1.x, x1.y, x1.z, x1.w};
      const float bv[4] = {b4.x, b4.y, b4.z, b4.w};
#pragma unroll
      for (int i = 0; i < 8; ++i)
#pragma unroll
        for (int j = 0; j < 4; ++j)
          acc[i][j] = fmaf(av[i], bv[j], acc[i][j]);
    }
  }
#pragma unroll
  for (int i = 0; i < 8; ++i) {
    float4 o;
    o.x = acc[i][0]; o.y = acc[i][1]; o.z = acc[i][2]; o.w = acc[i][3];
    *(float4*)(Cp + (long)(row0 + rm * 8 + i) * DMODEL + rn * 4) = o;
  }
}

// ---- out = LayerNorm(X + R) * g + be ----
__global__ __launch_bounds__(256) void ln_kernel(
    const float* __restrict__ X, const float* __restrict__ R,
    const float* __restrict__ g, const float* __restrict__ be,
    float* __restrict__ Out)
{
  __shared__ float red[8];
  const int tid = threadIdx.x;
  const long row = blockIdx.x;
  const float4 xv = *(const float4*)(X + row * DMODEL + tid * 4);
  const float4 rv = *(const float4*)(R + row * DMODEL + tid * 4);
  const float v0 = xv.x + rv.x, v1 = xv.y + rv.y, v2 = xv.z + rv.z, v3 = xv.w + rv.w;
  float s = waveSum((v0 + v1) + (v2 + v3));
  const int wv = tid >> 6, ln = tid & 63;
  if (ln == 0) red[wv] = s;
  __syncthreads();
  const float mu = (red[0] + red[1] + red[2] + red[3]) * (1.0f / DMODEL);
  const float d0 = v0 - mu, d1 = v1 - mu, d2 = v2 - mu, d3 = v3 - mu;
  float sq = waveSum(d0 * d0 + d1 * d1 + d2 * d2 + d3 * d3);
  if (ln == 0) red[4 + wv] = sq;
  __syncthreads();
  const float var = (red[4] + red[5] + red[6] + red[7]) * (1.0f / DMODEL);
  const float rstd = 1.0f / sqrtf(var + 1e-5f);
  const float4 gv = *(const float4*)(g + tid * 4);
  const float4 bv = *(const float4*)(be + tid * 4);
  float4 o;
  o.x = d0 * rstd * gv.x + bv.x;
  o.y = d1 * rstd * gv.y + bv.y;
  o.z = d2 * rstd * gv.z + bv.z;
  o.w = d3 * rstd * gv.w + bv.w;
  *(float4*)(Out + row * DMODEL + tid * 4) = o;
}

// ---- final softmax over V=32000, in place ----
__global__ __launch_bounds__(256) void softmax_vocab_kernel(float* __restrict__ P)
{
  __shared__ float red[8];
  const int tid = threadIdx.x;
  float4* p = (float4*)(P + (long)blockIdx.x * VOCAB);
  float m = -3.4e38f;
  for (int i = tid; i < VOCAB / 4; i += 256) {
    const float4 v = p[i];
    m = fmaxf(m, fmaxf(fmaxf(v.x, v.y), fmaxf(v.z, v.w)));
  }
  m = waveMax(m);
  const int wv = tid >> 6, ln = tid & 63;
  if (ln == 0) red[wv] = m;
  __syncthreads();
  m = fmaxf(fmaxf(red[0], red[1]), fmaxf(red[2], red[3]));
  float s = 0.f;
  for (int i = tid; i < VOCAB / 4; i += 256) {
    const float4 v = p[i];
    s += expf(v.x - m) + expf(v.y - m) + expf(v.z - m) + expf(v.w - m);
  }
  s = waveSum(s);
  if (ln == 0) red[4 + wv] = s;
  __syncthreads();
  const float inv = 1.0f / (red[4] + red[5] + red[6] + red[7]);
  for (int i = tid; i < VOCAB / 4; i += 256) {
    float4 v = p[i];
    v.x = expf(v.x - m) * inv;
    v.y = expf(v.y - m) * inv;
    v.z = expf(v.z - m) * inv;
    v.w = expf(v.w - m) * inv;
    p[i] = v;
  }
}

extern "C" void kernel_launch(void* const* d_in, const int* in_sizes, int n_in,
                              void* d_out, int out_size, void* d_ws, size_t ws_size,
                              hipStream_t stream)
{
  (void)in_sizes; (void)n_in; (void)out_size; (void)ws_size;
  const int* src = (const int*)d_in[0];
  const int* tgt = (const int*)d_in[1];
  const float* enc_emb = (const float*)d_in[2];
  const float* dec_emb = (const float*)d_in[3];
  const float* eWq = (const float*)d_in[4];
  const float* eWk = (const float*)d_in[5];
  const float* eWv = (const float*)d_in[6];
  const float* eWo = (const float*)d_in[7];
  const float* eBq = (const float*)d_in[8];
  const float* eBk = (const float*)d_in[9];
  const float* eBv = (const float*)d_in[10];
  const float* eBo = (const float*)d_in[11];
  const float* eL1g = (const float*)d_in[12];
  const float* eL1b = (const float*)d_in[13];
  const float* eL2g = (const float*)d_in[14];
  const float* eL2b = (const float*)d_in[15];
  const float* eF1  = (const float*)d_in[16];
  const float* eF1b = (const float*)d_in[17];
  const float* eF2  = (const float*)d_in[18];
  const float* eF2b = (const float*)d_in[19];
  const float* dsWq = (const float*)d_in[20];
  const float* dsWk = (const float*)d_in[21];
  const float* dsWv = (const float*)d_in[22];
  const float* dsWo = (const float*)d_in[23];
  const float* dcWq = (const float*)d_in[24];
  const float* dcWk = (const float*)d_in[25];
  const float* dcWv = (const float*)d_in[26];
  const float* dcWo = (const float*)d_in[27];
  const float* dsBq = (const float*)d_in[28];
  const float* dsBk = (const float*)d_in[29];
  const float* dsBv = (const float*)d_in[30];
  const float* dsBo = (const float*)d_in[31];
  const float* dcBq = (const float*)d_in[32];
  const float* dcBk = (const float*)d_in[33];
  const float* dcBv = (const float*)d_in[34];
  const float* dcBo = (const float*)d_in[35];
  const float* dL1g = (const float*)d_in[36];
  const float* dL2g = (const float*)d_in[37];
  const float* dL3g = (const float*)d_in[38];
  const float* dL1b = (const float*)d_in[39];
  const float* dL2b = (const float*)d_in[40];
  const float* dL3b = (const float*)d_in[41];
  const float* dF1  = (const float*)d_in[42];
  const float* dF1b = (const float*)d_in[43];
  const float* dF2  = (const float*)d_in[44];
  const float* dF2b = (const float*)d_in[45];
  const float* fW   = (const float*)d_in[46];
  const float* fb   = (const float*)d_in[47];

  // ---- workspace carve (total 125.97 MB, matches round-1 footprint) ----
  float* wp = (float*)d_ws;
  float* cosT = wp;   wp += SEQLEN * 32;          // 16384
  float* sinT = wp;   wp += SEQLEN * 32;
  float* fusedB = wp; wp += 3072;
  float* xb = wp;     wp += (long)MROWS * DMODEL; // enc stream / memory
  float* yb = wp;     wp += (long)MROWS * DMODEL; // dec stream
  float* ab = wp;     wp += (long)MROWS * DMODEL; // attention concat out
  float* pb = wp;     wp += (long)MROWS * DMODEL; // branch output
  float* qkv = wp;    wp += (long)MROWS * 3072;   // fused Q|K|V
  float* creg = wp;                               // 16,777,216 floats, time-aliased
  float* scores = creg;
  // attention weights (live before scores / after pv)
  unsigned short* aWh = (unsigned short*)creg;                 // 3072x1024
  unsigned short* aWl = aWh + 3072 * 1024;
  unsigned short* oWh = (unsigned short*)creg;                 // reused post-PV
  unsigned short* oWl = oWh + 1024 * 1024;
  // ffn (ffnbuf + 4 weight bufs, all within creg)
  float* ffnbuf = creg;                                        // 2048x4096
  unsigned short* f1h = (unsigned short*)(creg + (long)MROWS * DFFN);
  unsigned short* f1l = f1h + (long)DFFN * DMODEL;
  unsigned short* f2h = f1l + (long)DFFN * DMODEL;
  unsigned short* f2l = f2h + (long)DFFN * DMODEL;
  // vocab chunks (16000 cols)
  unsigned short* vh = (unsigned short*)creg;
  unsigned short* vl = vh + (long)16000 * 1024;

  const long DD = (long)DMODEL * DMODEL;
  const long DF = (long)DMODEL * DFFN;

  rope_tab_kernel<<<(SEQLEN * 32) / 256, 256, 0, stream>>>(cosT, sinT);

  auto attention = [&](float* q_in, float* kv_in,
                       const float* Wq, const float* Bq,
                       const float* Wk, const float* Bk,
                       const float* Wv, const float* Bv,
                       const float* Wo, const float* Bo,
                       const int* tok, int causal) {
    // convert weights -> aWh/aWl rows {0,1024,2048}
    wconv_kernel<<<dim3(32, 16), 256, 0, stream>>>(Wq, aWh, aWl, 1024, 1024, 0, 0);
    wconv_kernel<<<dim3(32, 16), 256, 0, stream>>>(Wk, aWh, aWl, 1024, 1024, 0, 1024);
    wconv_kernel<<<dim3(32, 16), 256, 0, stream>>>(Wv, aWh, aWl, 1024, 1024, 0, 2048);
    bias3_kernel<<<12, 256, 0, stream>>>(Bq, Bk, Bv, fusedB);
    if (q_in == kv_in) {
      // fused QKV: N=3072
      gemm_bf16_kernel<128><<<dim3(16, 24), 256, 0, stream>>>(
          q_in, aWh, aWl, fusedB, qkv, 1024, 3072, 0);
    } else {
      gemm_bf16_kernel<64><<<dim3(32, 8), 256, 0, stream>>>(
          q_in, aWh, aWl, fusedB, qkv, 1024, 3072, 0);
      gemm_bf16_kernel<128><<<dim3(16, 16), 256, 0, stream>>>(
          kv_in, aWh + (long)1024 * 1024, aWl + (long)1024 * 1024,
          fusedB + 1024, qkv + 1024, 1024, 3072, 0);
    }
    rope_kernel<<<(MROWS * NHEAD * 32) / 256, 256, 0, stream>>>(qkv, 3072, cosT, sinT);
    rope_kernel<<<(MROWS * NHEAD * 32) / 256, 256, 0, stream>>>(qkv + 1024, 3072, cosT, sinT);
    scores_kernel<<<dim3(8, 8, 64), 256, 0, stream>>>(
        qkv, qkv + 1024, 3072, 3072, scores, tok, causal);
    softmax512_kernel<<<(64 * SEQLEN) / 4, 256, 0, stream>>>(scores);
    pv_kernel<<<dim3(4, 1, 64), 256, 0, stream>>>(scores, qkv + 2048, ab);
    // O projection (scores now dead -> reuse creg for Wo)
    wconv_kernel<<<dim3(32, 16), 256, 0, stream>>>(Wo, oWh, oWl, 1024, 1024, 0, 0);
    gemm_bf16_kernel<64><<<dim3(32, 8), 256, 0, stream>>>(
        ab, oWh, oWl, Bo, pb, 1024, 1024, 0);
  };

  auto ffn = [&](float* x, const float* W1, const float* B1,
                 const float* W2, const float* B2) {
    wconv_kernel<<<dim3(32, 64), 256, 0, stream>>>(W1, f1h, f1l, 1024, 4096, 0, 0);
    wconv_kernel<<<dim3(128, 16), 256, 0, stream>>>(W2, f2h, f2l, 4096, 1024, 0, 0);
    gemm_bf16_kernel<128><<<dim3(16, 32), 256, 0, stream>>>(
        x, f1h, f1l, B1, ffnbuf, 1024, 4096, 1);
    gemm_bf16_kernel<64><<<dim3(32, 8), 256, 0, stream>>>(
        ffnbuf, f2h, f2l, B2, pb, 4096, 1024, 0);
  };

  // -------- encoder --------
  embed_kernel<<<MROWS, 256, 0, stream>>>(src, enc_emb, xb);
  for (int l = 0; l < NLAYER; ++l) {
    attention(xb, xb, eWq + l * DD, eBq + l * DMODEL, eWk + l * DD, eBk + l * DMODEL,
              eWv + l * DD, eBv + l * DMODEL, eWo + l * DD, eBo + l * DMODEL, src, 0);
    ln_kernel<<<MROWS, 256, 0, stream>>>(xb, pb, eL1g + l * DMODEL, eL1b + l * DMODEL, xb);
    ffn(xb, eF1 + l * DF, eF1b + l * DFFN, eF2 + l * DF, eF2b + l * DMODEL);
    ln_kernel<<<MROWS, 256, 0, stream>>>(xb, pb, eL2g + l * DMODEL, eL2b + l * DMODEL, xb);
  }
  // -------- decoder --------
  embed_kernel<<<MROWS, 256, 0, stream>>>(tgt, dec_emb, yb);
  for (int l = 0; l < NLAYER; ++l) {
    attention(yb, yb, dsWq + l * DD, dsBq + l * DMODEL, dsWk + l * DD, dsBk + l * DMODEL,
              dsWv + l * DD, dsBv + l * DMODEL, dsWo + l * DD, dsBo + l * DMODEL, tgt, 1);
    ln_kernel<<<MROWS, 256, 0, stream>>>(yb, pb, dL1g + l * DMODEL, dL1b + l * DMODEL, yb);
    attention(yb, xb, dcWq + l * DD, dcBq + l * DMODEL, dcWk + l * DD, dcBk + l * DMODEL,
              dcWv + l * DD, dcBv + l * DMODEL, dcWo + l * DD, dcBo + l * DMODEL, src, 0);
    ln_kernel<<<MROWS, 256, 0, stream>>>(yb, pb, dL2g + l * DMODEL, dL2b + l * DMODEL, yb);
    ffn(yb, dF1 + l * DF, dF1b + l * DFFN, dF2 + l * DF, dF2b + l * DMODEL);
    ln_kernel<<<MROWS, 256, 0, stream>>>(yb, pb, dL3g + l * DMODEL, dL3b + l * DMODEL, yb);
  }
  // -------- final projection (2 chunks of 16000 cols) + softmax --------
  float* outp = (float*)d_out;
  for (int c = 0; c < 2; ++c) {
    const int c0 = c * 16000;
    wconv_kernel<<<dim3(32, 250), 256, 0, stream>>>(fW, vh, vl, 1024, VOCAB, c0, 0);
    gemm_bf16_kernel<128><<<dim3(16, 125), 256, 0, stream>>>(
        yb, vh, vl, fb + c0, outp + c0, 1024, VOCAB, 0);
  }
  softmax_vocab_kernel<<<MROWS, 256, 0, stream>>>(outp);
}